// Round 12
// baseline (1320.084 us; speedup 1.0000x reference)
//
#include <hip/hip_runtime.h>
#include <math.h>

#define BB 128
#define TT 2048
#define II 128
#define UU 256
#define OO 128

typedef __attribute__((ext_vector_type(8))) short bf16x8;
typedef __attribute__((ext_vector_type(4))) float f32x4;

#define MFMA16(a, b, cacc) __builtin_amdgcn_mfma_f32_16x16x32_bf16(a, b, cacc, 0, 0, 0)

// LDS-only barrier (rule 18): orders LDS ops without draining vmcnt.
__device__ __forceinline__ void bar_lds() {
    __builtin_amdgcn_sched_barrier(0);
    asm volatile("s_waitcnt lgkmcnt(0)" ::: "memory");
    __builtin_amdgcn_s_barrier();
    __builtin_amdgcn_sched_barrier(0);
}

// float -> bf16 round-to-nearest-even
__device__ __forceinline__ short f2bf(float f) {
    unsigned u = __float_as_uint(f);
    unsigned r = (u + 0x7FFFu + ((u >> 16) & 1u)) >> 16;
    return (short)r;
}

__device__ __forceinline__ bf16x8 loadf8(const float* p) {
    float4 va = *reinterpret_cast<const float4*>(p);
    float4 vb = *reinterpret_cast<const float4*>(p + 4);
    bf16x8 v;
    v[0] = f2bf(va.x); v[1] = f2bf(va.y); v[2] = f2bf(va.z); v[3] = f2bf(va.w);
    v[4] = f2bf(vb.x); v[5] = f2bf(vb.y); v[6] = f2bf(vb.z); v[7] = f2bf(vb.w);
    return v;
}

// ---------------- Kernel 1: input projection as MFMA GEMM -----------------
// (unchanged, validated round 11 — near HBM floor)
__global__ __launch_bounds__(256, 2) void k_inproj(
    const float* __restrict__ x, const float* __restrict__ Wih,
    const float* __restrict__ bih, const float* __restrict__ bhh,
    float* __restrict__ xp)
{
    __shared__ __align__(16) short xs[64 * 128];   // 16 KB bf16, swizzled
    const int tid = threadIdx.x;
    const int w = tid >> 6;
    const int lane = tid & 63;
    const int g = lane >> 4;
    const int c = lane & 15;
    bf16x8 wb[4][4];
    float bias[4];
    #pragma unroll
    for (int nt = 0; nt < 4; ++nt) {
        const int u = w * 64 + nt * 16 + c;
        #pragma unroll
        for (int kt = 0; kt < 4; ++kt)
            wb[nt][kt] = loadf8(&Wih[(size_t)u * II + kt * 32 + g * 8]);
        bias[nt] = bih[u] + bhh[u];
    }
    const int srow = tid >> 2, sq = tid & 3;       // staging: 4 thr/row
    const int ntiles = (BB * TT) / 64;             // 4096
    for (int tile = blockIdx.x; tile < ntiles; tile += gridDim.x) {
        const size_t rowbase = (size_t)tile * 64;
        #pragma unroll
        for (int t2 = 0; t2 < 4; ++t2) {
            int n = sq * 4 + t2;                   // 16B chunk index 0..15
            const float* src = &x[(rowbase + srow) * II + n * 8];
            bf16x8 v = loadf8(src);
            int off = srow * 128 + ((n * 8) ^ ((srow & 7) << 3));
            *reinterpret_cast<bf16x8*>(&xs[off]) = v;
        }
        __syncthreads();
        #pragma unroll
        for (int mt = 0; mt < 4; ++mt) {
            const int row = mt * 16 + c;
            bf16x8 af[4];
            #pragma unroll
            for (int kt = 0; kt < 4; ++kt)
                af[kt] = *reinterpret_cast<const bf16x8*>(
                    &xs[row * 128 + ((kt * 32 + g * 8) ^ ((c & 7) << 3))]);
            f32x4 acc[4];
            #pragma unroll
            for (int nt = 0; nt < 4; ++nt) acc[nt] = (f32x4){0.f,0.f,0.f,0.f};
            #pragma unroll
            for (int kt = 0; kt < 4; ++kt)
                #pragma unroll
                for (int nt = 0; nt < 4; ++nt)
                    acc[nt] = MFMA16(af[kt], wb[nt][kt], acc[nt]);
            #pragma unroll
            for (int nt = 0; nt < 4; ++nt)
                #pragma unroll
                for (int r = 0; r < 4; ++r)
                    xp[(rowbase + mt * 16 + g * 4 + r) * UU + w * 64 + nt * 16 + c]
                        = acc[nt][r] + bias[nt];
        }
        __syncthreads();
    }
}

// ---------------- Kernel 2: serial recurrence (4 waves, 32 MFMA/wave) -----
// 1 block/batch, 256 thr = 4 waves (1/SIMD, launch_bounds(256,1) -> 512
// VGPR budget). Wave w owns 4 n-tiles (64 u): bq[4][8] = 128 VGPR resident.
// Per step: 8 broadcast ds_read_b128 (32/step/CU, HALF of r8) feed 32 MFMA
// into 8 acc slots (2 per n-tile, chain depth 4). Lane (g,c) finalizes the
// n-tile pair {(g&1)*2, (g&1)*2+1}: uA = w*64+(g&1)*32+c, uB = uA+16.
// g<2 lanes write h_raw (fp32) global; g>=2 write masked bf16 LDS carry.
// All acc/pair selection is compile-time / ternary (rule 20).
__global__ __launch_bounds__(256, 1) void k_rnn(
    const float* __restrict__ Whh, float* __restrict__ xph)
{
    __shared__ __align__(16) short hbuf[2 * 256];  // 2 x 256 bf16 = 1 KB
    const int tid = threadIdx.x;
    const int w = tid >> 6;          // wave 0..3 -> u-range w*64..w*64+63
    const int lane = tid & 63;
    const int g = lane >> 4;
    const int c = lane & 15;
    bf16x8 bq[4][8];
    #pragma unroll
    for (int nt = 0; nt < 4; ++nt) {
        const int ub = w * 64 + nt * 16 + c;
        #pragma unroll
        for (int kt = 0; kt < 8; ++kt)
            bq[nt][kt] = loadf8(&Whh[(size_t)ub * UU + kt * 32 + g * 8]);
    }
    const int uA = w * 64 + (g & 1) * 32 + c;      // owned n-tile pair
    const int uB = uA + 16;
    const bool gl = (g < 2);
    const bool killA = (uA == 3) || (uA == 7);     // uB >= 16: never killed
    if (tid < 256) reinterpret_cast<int*>(hbuf)[tid] = 0;
    __syncthreads();

    float* rowp = xph + (size_t)blockIdx.x * (size_t)TT * UU;
    float xpvA = rowp[uA],      xpvB = rowp[uB];
    float xpnA = rowp[UU + uA], xpnB = rowp[UU + uB];

    auto step = [&](int t, int p) {
        int tn = t + 2; tn = (tn < TT) ? tn : (TT - 1);
        float xpn2A = rowp[(size_t)tn * UU + uA];
        float xpn2B = rowp[(size_t)tn * UU + uB];
        const bf16x8* hb = reinterpret_cast<const bf16x8*>(hbuf + p * 256);
        f32x4 a0a = {0.f,0.f,0.f,0.f}, a0b = {0.f,0.f,0.f,0.f};
        f32x4 a1a = {0.f,0.f,0.f,0.f}, a1b = {0.f,0.f,0.f,0.f};
        f32x4 a2a = {0.f,0.f,0.f,0.f}, a2b = {0.f,0.f,0.f,0.f};
        f32x4 a3a = {0.f,0.f,0.f,0.f}, a3b = {0.f,0.f,0.f,0.f};
        #pragma unroll
        for (int kt = 0; kt < 8; kt += 2) {
            bf16x8 f0 = hb[kt * 4 + g];
            bf16x8 f1 = hb[(kt + 1) * 4 + g];
            a0a = MFMA16(f0, bq[0][kt],     a0a);
            a1a = MFMA16(f0, bq[1][kt],     a1a);
            a2a = MFMA16(f0, bq[2][kt],     a2a);
            a3a = MFMA16(f0, bq[3][kt],     a3a);
            a0b = MFMA16(f1, bq[0][kt + 1], a0b);
            a1b = MFMA16(f1, bq[1][kt + 1], a1b);
            a2b = MFMA16(f1, bq[2][kt + 1], a2b);
            a3b = MFMA16(f1, bq[3][kt + 1], a3b);
        }
        float d0 = a0a[0] + a0b[0];                // nt0 full sum (rows repl.)
        float d1 = a1a[0] + a1b[0];
        float d2 = a2a[0] + a2b[0];
        float d3 = a3a[0] + a3b[0];
        float dA = (g & 1) ? d2 : d0;
        float dB = (g & 1) ? d3 : d1;
        float sA = dA + xpvA;
        float sB = dB + xpvB;
        float hrA = 1.0f - 2.0f / (__expf(2.0f * sA) + 1.0f);
        float hrB = 1.0f - 2.0f / (__expf(2.0f * sB) + 1.0f);
        if (gl) {
            rowp[(size_t)t * UU + uA] = hrA;               // h_raw (fp32)
            rowp[(size_t)t * UU + uB] = hrB;
        } else {
            hbuf[(p ^ 1) * 256 + uA] = killA ? (short)0 : f2bf(hrA);
            hbuf[(p ^ 1) * 256 + uB] = f2bf(hrB);
        }
        bar_lds();
        xpvA = xpnA; xpnA = xpn2A;
        xpvB = xpnB; xpnB = xpn2B;
    };
    for (int t = 0; t < TT; t += 2) { step(t, 0); step(t + 1, 1); }
}

// ---------------- Kernel 3: readout as MFMA GEMM + mask fix-up ------------
// (unchanged, validated round 11 — near HBM floor)
__global__ __launch_bounds__(256, 2) void k_readout(
    const float* __restrict__ Wfc, const float* __restrict__ bfc,
    float* __restrict__ hraw, float* __restrict__ outR)
{
    __shared__ __align__(16) short hs[64 * 256];   // 32 KB bf16, swizzled
    const int tid = threadIdx.x;
    const int w = tid >> 6;
    const int lane = tid & 63;
    const int g = lane >> 4;
    const int c = lane & 15;
    bf16x8 wb[2][8];
    float bias[2];
    #pragma unroll
    for (int nt = 0; nt < 2; ++nt) {
        const int o = w * 32 + nt * 16 + c;
        #pragma unroll
        for (int kt = 0; kt < 8; ++kt)
            wb[nt][kt] = loadf8(&Wfc[(size_t)o * UU + kt * 32 + g * 8]);
        bias[nt] = bfc[o];
    }
    const int srow = tid >> 2, sq = tid & 3;       // staging: 4 thr/row
    const int ntiles = (BB * TT) / 64;             // 4096
    for (int tile = blockIdx.x; tile < ntiles; tile += gridDim.x) {
        const size_t rowbase = (size_t)tile * 64;
        #pragma unroll
        for (int t2 = 0; t2 < 8; ++t2) {
            int n = sq * 8 + t2;                   // 16B chunk 0..31
            const float* src = &hraw[(rowbase + srow) * UU + n * 8];
            bf16x8 v = loadf8(src);
            int off = srow * 256 + ((n * 8) ^ ((srow & 7) << 3));
            *reinterpret_cast<bf16x8*>(&hs[off]) = v;
        }
        __syncthreads();
        // raw values staged: zero killed units in the global hs output
        if (tid < 128) {
            int r = tid >> 1, col = (tid & 1) ? 7 : 3;
            hraw[(rowbase + r) * UU + col] = 0.f;
        }
        #pragma unroll
        for (int mt = 0; mt < 4; ++mt) {
            const int row = mt * 16 + c;
            f32x4 acc[2];
            acc[0] = (f32x4){0.f,0.f,0.f,0.f};
            acc[1] = (f32x4){0.f,0.f,0.f,0.f};
            #pragma unroll
            for (int kt = 0; kt < 8; ++kt) {
                bf16x8 af = *reinterpret_cast<const bf16x8*>(
                    &hs[row * 256 + ((kt * 32 + g * 8) ^ ((c & 7) << 3))]);
                acc[0] = MFMA16(af, wb[0][kt], acc[0]);
                acc[1] = MFMA16(af, wb[1][kt], acc[1]);
            }
            #pragma unroll
            for (int nt = 0; nt < 2; ++nt)
                #pragma unroll
                for (int r = 0; r < 4; ++r)
                    outR[(rowbase + mt * 16 + g * 4 + r) * OO + w * 32 + nt * 16 + c]
                        = acc[nt][r] + bias[nt];
        }
        __syncthreads();
    }
}

extern "C" void kernel_launch(void* const* d_in, const int* in_sizes, int n_in,
                              void* d_out, int out_size, void* d_ws, size_t ws_size,
                              hipStream_t stream) {
    const float* x   = (const float*)d_in[0];
    const float* Wih = (const float*)d_in[1];
    const float* Whh = (const float*)d_in[2];
    const float* bih = (const float*)d_in[3];
    const float* bhh = (const float*)d_in[4];
    const float* Wfc = (const float*)d_in[5];
    const float* bfc = (const float*)d_in[6];
    float* outR = (float*)d_out;                       // readouts [B,T,O]
    float* outH = outR + (size_t)BB * TT * OO;         // hs       [B,T,U]

    k_inproj<<<512, 256, 0, stream>>>(x, Wih, bih, bhh, outH);
    k_rnn<<<128, 256, 0, stream>>>(Whh, outH);
    k_readout<<<512, 256, 0, stream>>>(Wfc, bfc, outH, outR);
}